// Round 8
// baseline (893.095 us; speedup 1.0000x reference)
//
#include <hip/hip_runtime.h>
#include <math.h>

#define NN 100000
#define NE 1600000
#define HD 32
#define NG 64
#define NC 8

#define P 256         // partitions (by target col range)
#define PART 391      // nodes per partition; 391*256 = 100096 >= NN
#define SCAP 7000     // staging capacity per partition (Poisson(6250) + 9 sigma)
#define CH 8192       // edges per k_bin block
#define NBIN ((NE + CH - 1) / CH)    // 196
#define GEMM0_BLOCKS (NN / 8)        // 12500

__device__ __forceinline__ float bf2f(unsigned short u) {
    return __uint_as_float(((unsigned int)u) << 16);
}
__device__ __forceinline__ unsigned short f2bf(float f) {
    unsigned int b = __float_as_uint(f);
    b = (b + 0x7FFFu + ((b >> 16) & 1u)) >> 16;  // RNE
    return (unsigned short)b;
}

// ---------- phase 1: bin edges into col-range partitions ----------
// staging entry: x = col_lo | (row << 9)  (col_lo < 391 < 512), y = w bits
__global__ __launch_bounds__(256) void k_bin(const int* __restrict__ row,
                                             const int* __restrict__ col,
                                             const float* __restrict__ w,
                                             int* __restrict__ pcnt,
                                             uint2* __restrict__ staging) {
    __shared__ int scol[CH];   // 32 KB
    __shared__ int hist[P];
    __shared__ int base_[P];
    int tid = threadIdx.x;
    int e0 = blockIdx.x * CH;
    int nrem = min(CH, NE - e0);
    hist[tid] = 0;
    __syncthreads();
    for (int i = tid; i < nrem; i += 256) {
        int c = col[e0 + i];
        scol[i] = c;
        atomicAdd(&hist[(unsigned)c / PART], 1);
    }
    __syncthreads();
    int h = hist[tid];
    base_[tid] = h ? atomicAdd(&pcnt[tid], h) : 0;
    __syncthreads();
    hist[tid] = 0;
    __syncthreads();
    for (int i = tid; i < nrem; i += 256) {
        int c = scol[i];
        int p = (unsigned)c / PART;
        int pos = base_[p] + atomicAdd(&hist[p], 1);
        uint2 v;
        v.x = (unsigned)(c - p * PART) | ((unsigned)row[e0 + i] << 9);
        v.y = __float_as_uint(w[e0 + i]);
        staging[(size_t)p * SCAP + pos] = v;
    }
}

// ---------- phase 2 (fused with gemm0): dinv per node  ||  h1 = x @ W1 ----------
__global__ __launch_bounds__(256) void k_dinv_gemm0(const int* __restrict__ pcnt,
                                                    const uint2* __restrict__ staging,
                                                    float* __restrict__ dinv,
                                                    const float* __restrict__ x,
                                                    const float* __restrict__ W1,
                                                    unsigned short* __restrict__ h1) {
    int tid = threadIdx.x;
    if (blockIdx.x < P) {
        __shared__ float wsum[PART];
        int p = blockIdx.x;
        int m = pcnt[p];
        for (int i = tid; i < PART; i += 256) wsum[i] = 0.0f;
        __syncthreads();
        const uint2* st = staging + (size_t)p * SCAP;
        for (int i = tid; i < m; i += 256) {
            uint2 v = st[i];
            atomicAdd(&wsum[v.x & 511], __uint_as_float(v.y));
        }
        __syncthreads();
        for (int i = tid; i < PART; i += 256) {
            int n = p * PART + i;
            if (n < NN) dinv[n] = rsqrtf(1.0f + wsum[i]);
        }
    } else {
        __shared__ float sW[32 * 32];
        __shared__ float sX[8 * 32];
        int base = (blockIdx.x - P) * 8;
        ((float4*)sW)[tid] = ((const float4*)W1)[tid];
        if (tid < 64) ((float4*)sX)[tid] = ((const float4*)(x + (size_t)base * 32))[tid];
        __syncthreads();
        int c = tid & 31, nl = tid >> 5;
        float acc = 0.0f;
#pragma unroll
        for (int k = 0; k < 32; ++k) acc = fmaf(sX[nl * 32 + k], sW[k * 32 + c], acc);
        h1[(size_t)(base + nl) * 32 + c] = f2bf(acc);
    }
}

// ---------- aggregation: one block per partition, LDS accumulator tile ----------
// MODE 0: hout = bf16( relu(agg + bias) @ Wn )   MODE 1: hout = bf16(relu(agg + bias))
template <int MODE>
__global__ __launch_bounds__(1024) void k_agg(const unsigned short* __restrict__ hb,
                                              const int* __restrict__ pcnt,
                                              const uint2* __restrict__ staging,
                                              const float* __restrict__ dinv,
                                              const float* __restrict__ bias,
                                              const float* __restrict__ Wn,
                                              unsigned short* __restrict__ hout) {
    __shared__ float acc[PART * 33];   // 51.6 KB, stride 33 vs bank conflicts
    __shared__ float sdc[PART];
    __shared__ float sW[32 * 32];
    int p = blockIdx.x, tid = threadIdx.x;
    int m = pcnt[p];
    if (MODE == 0 && tid < 256) ((float4*)sW)[tid] = ((const float4*)Wn)[tid];
    for (int i = tid; i < PART; i += 1024) {
        int n = p * PART + i;
        sdc[i] = (n < NN) ? dinv[n] : 0.0f;
    }
    __syncthreads();
    // init accumulator with self-loop term dinv^2 * h[n]
    for (int u = tid; u < PART * 8; u += 1024) {
        int i = u >> 3, q = u & 7;
        int n = p * PART + i;
        float ax = 0.f, ay = 0.f, az = 0.f, aw = 0.f;
        if (n < NN) {
            float sl = sdc[i] * sdc[i];
            ushort4 hv = *((const ushort4*)(hb + (size_t)n * 32) + q);
            ax = sl * bf2f(hv.x); ay = sl * bf2f(hv.y);
            az = sl * bf2f(hv.z); aw = sl * bf2f(hv.w);
        }
        int b = i * 33 + q * 4;
        acc[b + 0] = ax; acc[b + 1] = ay; acc[b + 2] = az; acc[b + 3] = aw;
    }
    __syncthreads();
    // edge stream: 8 lanes per edge, 8-deep pipelined
    const uint2* st = staging + (size_t)p * SCAP;
    int grp = tid >> 3, q = tid & 7;   // 128 edge-groups
    for (int base = grp; base < m; base += 128 * 8) {
        uint2 v[8]; float dr[8]; ushort4 hv[8];
#pragma unroll
        for (int j = 0; j < 8; ++j) {
            int i = base + j * 128;
            if (i < m) v[j] = st[i];
        }
#pragma unroll
        for (int j = 0; j < 8; ++j) {
            int i = base + j * 128;
            if (i < m) dr[j] = dinv[v[j].x >> 9];
        }
#pragma unroll
        for (int j = 0; j < 8; ++j) {
            int i = base + j * 128;
            if (i < m) hv[j] = *((const ushort4*)(hb + (size_t)(v[j].x >> 9) * 32) + q);
        }
#pragma unroll
        for (int j = 0; j < 8; ++j) {
            int i = base + j * 128;
            if (i < m) {
                int cl = v[j].x & 511;
                float nm = dr[j] * __uint_as_float(v[j].y) * sdc[cl];
                int b = cl * 33 + q * 4;
                atomicAdd(&acc[b + 0], nm * bf2f(hv[j].x));
                atomicAdd(&acc[b + 1], nm * bf2f(hv[j].y));
                atomicAdd(&acc[b + 2], nm * bf2f(hv[j].z));
                atomicAdd(&acc[b + 3], nm * bf2f(hv[j].w));
            }
        }
    }
    __syncthreads();
    // epilogue
    for (int u = tid; u < PART * 8; u += 1024) {
        int i = u >> 3, qq = u & 7;
        int n = p * PART + i;
        if (n >= NN) continue;
        int cb = qq * 4;
        ushort4 ou;
        if (MODE == 0) {
            float o0 = 0.f, o1 = 0.f, o2 = 0.f, o3 = 0.f;
            const float* ar = acc + i * 33;
#pragma unroll
            for (int kk = 0; kk < 32; ++kk) {
                float r = fmaxf(ar[kk] + bias[kk], 0.0f);
                const float* wr = sW + kk * 32 + cb;
                o0 = fmaf(r, wr[0], o0);
                o1 = fmaf(r, wr[1], o1);
                o2 = fmaf(r, wr[2], o2);
                o3 = fmaf(r, wr[3], o3);
            }
            ou.x = f2bf(o0); ou.y = f2bf(o1); ou.z = f2bf(o2); ou.w = f2bf(o3);
        } else {
            const float* ar = acc + i * 33 + cb;
            ou.x = f2bf(fmaxf(ar[0] + bias[cb + 0], 0.0f));
            ou.y = f2bf(fmaxf(ar[1] + bias[cb + 1], 0.0f));
            ou.z = f2bf(fmaxf(ar[2] + bias[cb + 2], 0.0f));
            ou.w = f2bf(fmaxf(ar[3] + bias[cb + 3], 0.0f));
        }
        *((ushort4*)(hout + (size_t)n * 32) + qq) = ou;
    }
}

// ---------- global mean pool (bf16 in, already relu+bias) + head + log_softmax ----------
__global__ __launch_bounds__(1024) void k_pool_head(const unsigned short* __restrict__ h3,
                                                    const int* __restrict__ batch,
                                                    const float* __restrict__ Wout,
                                                    const float* __restrict__ bout,
                                                    float* __restrict__ out) {
    int g = blockIdx.x;
    __shared__ int sb[2];
    if (threadIdx.x == 0) {
        int lo = 0, hi = NN;
        while (lo < hi) { int m = (lo + hi) >> 1; if (batch[m] < g) lo = m + 1; else hi = m; }
        sb[0] = lo;
        lo = 0; hi = NN;
        while (lo < hi) { int m = (lo + hi) >> 1; if (batch[m] < g + 1) lo = m + 1; else hi = m; }
        sb[1] = lo;
    }
    __syncthreads();
    int start = sb[0], end = sb[1];
    int c = threadIdx.x & 31, grp = threadIdx.x >> 5;
    float acc = 0.0f;
    for (int n = start + grp; n < end; n += 32)
        acc += bf2f(h3[(size_t)n * 32 + c]);
    __shared__ float red[32 * 32];
    red[grp * 32 + c] = acc;
    __syncthreads();
    __shared__ float pooled[32];
    if (threadIdx.x < 32) {
        float s = 0.0f;
#pragma unroll
        for (int gr = 0; gr < 32; ++gr) s += red[gr * 32 + threadIdx.x];
        pooled[threadIdx.x] = s / fmaxf((float)(end - start), 1.0f);
    }
    __syncthreads();
    __shared__ float slog[8];
    if (threadIdx.x < 8) {
        float l = bout[threadIdx.x];
#pragma unroll
        for (int k = 0; k < 32; ++k) l = fmaf(pooled[k], Wout[k * 8 + threadIdx.x], l);
        slog[threadIdx.x] = l;
    }
    __syncthreads();
    if (threadIdx.x < 8) {
        float m = slog[0];
#pragma unroll
        for (int i = 1; i < 8; ++i) m = fmaxf(m, slog[i]);
        float s = 0.0f;
#pragma unroll
        for (int i = 0; i < 8; ++i) s += expf(slog[i] - m);
        out[g * NC + threadIdx.x] = slog[threadIdx.x] - m - logf(s);
    }
}

extern "C" void kernel_launch(void* const* d_in, const int* in_sizes, int n_in,
                              void* d_out, int out_size, void* d_ws, size_t ws_size,
                              hipStream_t stream) {
    const float* x     = (const float*)d_in[0];
    const int*   eidx  = (const int*)d_in[1];
    const float* ew    = (const float*)d_in[2];
    const int*   batch = (const int*)d_in[3];
    const float* W1 = (const float*)d_in[4];
    const float* b1 = (const float*)d_in[5];
    const float* W2 = (const float*)d_in[6];
    const float* b2 = (const float*)d_in[7];
    const float* W3 = (const float*)d_in[8];
    const float* b3 = (const float*)d_in[9];
    const float* Wout = (const float*)d_in[10];
    const float* bout = (const float*)d_in[11];
    float* out = (float*)d_out;

    const int* row = eidx;        // sources
    const int* col = eidx + NE;   // targets

    // layout: B1 bf16 | B2 bf16 | staging | dinv | pcnt   (~28 MB)
    unsigned short* B1 = (unsigned short*)d_ws;                  // 6.4 MB
    unsigned short* B2 = B1 + (size_t)NN * HD;                   // 6.4 MB
    uint2* staging = (uint2*)(B2 + (size_t)NN * HD);             // 14.3 MB
    float* dinv = (float*)(staging + (size_t)P * SCAP);          // 0.4 MB
    int* pcnt = (int*)(dinv + NN);                               // 1 KB

    hipMemsetAsync(pcnt, 0, P * sizeof(int), stream);
    k_bin<<<NBIN, 256, 0, stream>>>(row, col, ew, pcnt, staging);
    k_dinv_gemm0<<<P + GEMM0_BLOCKS, 256, 0, stream>>>(pcnt, staging, dinv, x, W1, B1);
    k_agg<0><<<P, 1024, 0, stream>>>(B1, pcnt, staging, dinv, b1, W2, B2);
    k_agg<0><<<P, 1024, 0, stream>>>(B2, pcnt, staging, dinv, b2, W3, B1);
    k_agg<1><<<P, 1024, 0, stream>>>(B1, pcnt, staging, dinv, b3, nullptr, B2);
    k_pool_head<<<NG, 1024, 0, stream>>>(B2, batch, Wout, bout, out);
}

// Round 9
// 175.806 us; speedup vs baseline: 5.0800x; 5.0800x over previous
//
#include <hip/hip_runtime.h>
#include <math.h>

#define NN 100000
#define NE 1600000
#define HD 32
#define NG 64
#define NC 8

#define P 256         // partitions
#define PART 391      // nodes per partition; 391*256 = 100096 >= NN
#define SCAP 7000     // staging capacity per partition (Poisson(6250), +9 sigma)
#define CH 8192       // edges per k_bin block
#define NBIN ((NE + CH - 1) / CH)    // 196
#define NORM_BLOCKS (NN * 8 / 256)   // 3125 (gather grid)
#define GEMM0_BLOCKS (NN / 8)        // 12500

__device__ __forceinline__ float bf2f(unsigned short u) {
    return __uint_as_float(((unsigned int)u) << 16);
}
__device__ __forceinline__ unsigned short f2bf(float f) {
    unsigned int b = __float_as_uint(f);
    b = (b + 0x7FFFu + ((b >> 16) & 1u)) >> 16;  // RNE
    return (unsigned short)b;
}

// ---------- phase 1: bin edges into col-range partitions ----------
// staging entry: x = col_lo | (row << 9)  (col_lo < 391 < 512), y = w bits
__global__ __launch_bounds__(256) void k_bin(const int* __restrict__ row,
                                             const int* __restrict__ col,
                                             const float* __restrict__ w,
                                             int* __restrict__ pcnt,
                                             uint2* __restrict__ staging) {
    __shared__ int scol[CH];   // 32 KB
    __shared__ int hist[P];
    __shared__ int base_[P];
    int tid = threadIdx.x;
    int e0 = blockIdx.x * CH;
    int nrem = min(CH, NE - e0);
    hist[tid] = 0;
    __syncthreads();
    for (int i = tid; i < nrem; i += 256) {
        int c = col[e0 + i];
        scol[i] = c;
        atomicAdd(&hist[(unsigned)c / PART], 1);
    }
    __syncthreads();
    int h = hist[tid];
    base_[tid] = h ? atomicAdd(&pcnt[tid], h) : 0;
    __syncthreads();
    hist[tid] = 0;
    __syncthreads();
    for (int i = tid; i < nrem; i += 256) {
        int c = scol[i];
        int p = (unsigned)c / PART;
        int pos = base_[p] + atomicAdd(&hist[p], 1);
        uint2 v;
        v.x = (unsigned)(c - p * PART) | ((unsigned)row[e0 + i] << 9);
        v.y = __float_as_uint(w[e0 + i]);
        staging[(size_t)p * SCAP + pos] = v;
    }
}

// ---------- phase 2a (fused with gemm0): per-partition counts + dinv + CSR offsets ----------
__global__ __launch_bounds__(256) void k_csrA_gemm0(const int* __restrict__ pcnt,
                                                    const int* __restrict__ pbase,
                                                    const uint2* __restrict__ staging,
                                                    int* __restrict__ off,
                                                    int* __restrict__ cntg,
                                                    float* __restrict__ dinv,
                                                    const float* __restrict__ x,
                                                    const float* __restrict__ W1,
                                                    unsigned short* __restrict__ h1) {
    int tid = threadIdx.x;
    if (blockIdx.x < P) {
        __shared__ int cnt_l[PART];
        __shared__ float wsum[PART];
        __shared__ int sc[PART];
        int p = blockIdx.x;
        int m = pcnt[p], pb = pbase[p];
        for (int i = tid; i < PART; i += 256) { cnt_l[i] = 0; wsum[i] = 0.0f; }
        __syncthreads();
        const uint2* st = staging + (size_t)p * SCAP;
        for (int i = tid; i < m; i += 256) {
            uint2 v = st[i];
            int cl = v.x & 511;
            atomicAdd(&cnt_l[cl], 1);
            atomicAdd(&wsum[cl], __uint_as_float(v.y));
        }
        __syncthreads();
        for (int i = tid; i < PART; i += 256) sc[i] = cnt_l[i];
        __syncthreads();
        int i0 = tid, i1 = tid + 256;
#pragma unroll
        for (int d = 1; d < 512; d <<= 1) {
            int t0 = 0, t1 = 0;
            if (i0 < PART && i0 >= d) t0 = sc[i0 - d];
            if (i1 < PART && i1 >= d) t1 = sc[i1 - d];
            __syncthreads();
            if (i0 < PART) sc[i0] += t0;
            if (i1 < PART) sc[i1] += t1;
            __syncthreads();
        }
        for (int i = tid; i < PART; i += 256) {
            int n = p * PART + i;
            if (n < NN) {
                off[n] = pb + sc[i] - cnt_l[i];
                cntg[n] = cnt_l[i];
                dinv[n] = rsqrtf(1.0f + wsum[i]);
            }
        }
    } else {
        __shared__ float sW[32 * 32];
        __shared__ float sX[8 * 32];
        int base = (blockIdx.x - P) * 8;
        ((float4*)sW)[tid] = ((const float4*)W1)[tid];
        if (tid < 64) ((float4*)sX)[tid] = ((const float4*)(x + (size_t)base * 32))[tid];
        __syncthreads();
        int c = tid & 31, nl = tid >> 5;
        float acc = 0.0f;
#pragma unroll
        for (int k = 0; k < 32; ++k) acc = fmaf(sX[nl * 32 + k], sW[k * 32 + c], acc);
        h1[(size_t)(base + nl) * 32 + c] = f2bf(acc);
    }
}

// ---------- phase 2b: write final normalized pairs (LDS cursors, batched dinv reads) ----------
__global__ __launch_bounds__(512) void k_csr_b(const int* __restrict__ pcnt,
                                               const uint2* __restrict__ staging,
                                               const int* __restrict__ off,
                                               const float* __restrict__ dinv,
                                               float2* __restrict__ pairs) {
    __shared__ int cur[PART];
    __shared__ float sdc[PART];
    int p = blockIdx.x, tid = threadIdx.x;
    int m = pcnt[p];
    const uint2* st = staging + (size_t)p * SCAP;
    for (int i = tid; i < PART; i += 512) {
        int n = p * PART + i;
        cur[i] = (n < NN) ? off[n] : 0;
        sdc[i] = (n < NN) ? dinv[n] : 0.0f;
    }
    __syncthreads();
    for (int ib = tid; ib < m; ib += 512 * 4) {
        uint2 v[4];
        float dr[4];
#pragma unroll
        for (int j = 0; j < 4; ++j) {
            int i = ib + j * 512;
            if (i < m) v[j] = st[i];
        }
#pragma unroll
        for (int j = 0; j < 4; ++j) {
            int i = ib + j * 512;
            if (i < m) dr[j] = dinv[v[j].x >> 9];
        }
#pragma unroll
        for (int j = 0; j < 4; ++j) {
            int i = ib + j * 512;
            if (i < m) {
                int cl = v[j].x & 511;
                int pos = atomicAdd(&cur[cl], 1);
                float y = dr[j] * __uint_as_float(v[j].y) * sdc[cl];
                pairs[pos] = make_float2(__int_as_float((int)(v[j].x >> 9)), y);
            }
        }
    }
}

// ---------- gather (bf16 h): MODE 0 = fuse next GEMM, MODE 1 = final relu(agg+bias) ----------
template <int MODE>
__global__ __launch_bounds__(256) void k_gather(const unsigned short* __restrict__ hb,
                                                const int* __restrict__ off,
                                                const int* __restrict__ cntg,
                                                const float* __restrict__ dinv,
                                                const float2* __restrict__ pairs,
                                                const float* __restrict__ bias,
                                                const float* __restrict__ Wn,
                                                unsigned short* __restrict__ hout) {
    __shared__ float sW[32 * 32];
    __shared__ float srow[32 * 33];
    int tid = threadIdx.x;
    if (MODE == 0) ((float4*)sW)[tid] = ((const float4*)Wn)[tid];
    int t = blockIdx.x * 256 + tid;  // NN*8 exact
    int n = t >> 3, c4 = t & 7;
    int cn = cntg[n];
    const float2* pp = pairs + off[n];
    float di = dinv[n];
    float sl = di * di;
    ushort4 hu = *((const ushort4*)(hb + (size_t)n * 32) + c4);
    float4 acc = make_float4(sl * bf2f(hu.x), sl * bf2f(hu.y),
                             sl * bf2f(hu.z), sl * bf2f(hu.w));
    int k = 0;
    // 16-deep: 32 independent loads in flight per thread
    for (; k + 16 <= cn; k += 16) {
        float2 p[16];
#pragma unroll
        for (int j = 0; j < 16; ++j) p[j] = pp[k + j];
        ushort4 v[16];
#pragma unroll
        for (int j = 0; j < 16; ++j)
            v[j] = *((const ushort4*)(hb + (size_t)__float_as_int(p[j].x) * 32) + c4);
#pragma unroll
        for (int j = 0; j < 16; ++j) {
            acc.x = fmaf(p[j].y, bf2f(v[j].x), acc.x);
            acc.y = fmaf(p[j].y, bf2f(v[j].y), acc.y);
            acc.z = fmaf(p[j].y, bf2f(v[j].z), acc.z);
            acc.w = fmaf(p[j].y, bf2f(v[j].w), acc.w);
        }
    }
    for (; k + 8 <= cn; k += 8) {
        float2 p[8];
#pragma unroll
        for (int j = 0; j < 8; ++j) p[j] = pp[k + j];
        ushort4 v[8];
#pragma unroll
        for (int j = 0; j < 8; ++j)
            v[j] = *((const ushort4*)(hb + (size_t)__float_as_int(p[j].x) * 32) + c4);
#pragma unroll
        for (int j = 0; j < 8; ++j) {
            acc.x = fmaf(p[j].y, bf2f(v[j].x), acc.x);
            acc.y = fmaf(p[j].y, bf2f(v[j].y), acc.y);
            acc.z = fmaf(p[j].y, bf2f(v[j].z), acc.z);
            acc.w = fmaf(p[j].y, bf2f(v[j].w), acc.w);
        }
    }
    for (; k + 4 <= cn; k += 4) {
        float2 p[4];
#pragma unroll
        for (int j = 0; j < 4; ++j) p[j] = pp[k + j];
        ushort4 v[4];
#pragma unroll
        for (int j = 0; j < 4; ++j)
            v[j] = *((const ushort4*)(hb + (size_t)__float_as_int(p[j].x) * 32) + c4);
#pragma unroll
        for (int j = 0; j < 4; ++j) {
            acc.x = fmaf(p[j].y, bf2f(v[j].x), acc.x);
            acc.y = fmaf(p[j].y, bf2f(v[j].y), acc.y);
            acc.z = fmaf(p[j].y, bf2f(v[j].z), acc.z);
            acc.w = fmaf(p[j].y, bf2f(v[j].w), acc.w);
        }
    }
    for (; k < cn; ++k) {
        float2 p = pp[k];
        ushort4 v = *((const ushort4*)(hb + (size_t)__float_as_int(p.x) * 32) + c4);
        acc.x = fmaf(p.y, bf2f(v.x), acc.x);
        acc.y = fmaf(p.y, bf2f(v.y), acc.y);
        acc.z = fmaf(p.y, bf2f(v.z), acc.z);
        acc.w = fmaf(p.y, bf2f(v.w), acc.w);
    }
    int cb = c4 * 4;
    if (MODE == 0) {
        int ln = tid >> 3;
        srow[ln * 33 + cb + 0] = fmaxf(acc.x + bias[cb + 0], 0.0f);
        srow[ln * 33 + cb + 1] = fmaxf(acc.y + bias[cb + 1], 0.0f);
        srow[ln * 33 + cb + 2] = fmaxf(acc.z + bias[cb + 2], 0.0f);
        srow[ln * 33 + cb + 3] = fmaxf(acc.w + bias[cb + 3], 0.0f);
        __syncthreads();
        const float* rw = srow + ln * 33;
        float o0 = 0.f, o1 = 0.f, o2 = 0.f, o3 = 0.f;
#pragma unroll
        for (int kk = 0; kk < 32; ++kk) {
            float r = rw[kk];
            const float* wr = sW + kk * 32 + cb;
            o0 = fmaf(r, wr[0], o0);
            o1 = fmaf(r, wr[1], o1);
            o2 = fmaf(r, wr[2], o2);
            o3 = fmaf(r, wr[3], o3);
        }
        ushort4 ou;
        ou.x = f2bf(o0); ou.y = f2bf(o1); ou.z = f2bf(o2); ou.w = f2bf(o3);
        *((ushort4*)(hout + (size_t)n * 32) + c4) = ou;
    } else {
        ushort4 ou;
        ou.x = f2bf(fmaxf(acc.x + bias[cb + 0], 0.0f));
        ou.y = f2bf(fmaxf(acc.y + bias[cb + 1], 0.0f));
        ou.z = f2bf(fmaxf(acc.z + bias[cb + 2], 0.0f));
        ou.w = f2bf(fmaxf(acc.w + bias[cb + 3], 0.0f));
        *((ushort4*)(hout + (size_t)n * 32) + c4) = ou;
    }
}

// ---------- global mean pool (bf16 in, already relu+bias) + head + log_softmax ----------
__global__ __launch_bounds__(1024) void k_pool_head(const unsigned short* __restrict__ h3,
                                                    const int* __restrict__ batch,
                                                    const float* __restrict__ Wout,
                                                    const float* __restrict__ bout,
                                                    float* __restrict__ out) {
    int g = blockIdx.x;
    __shared__ int sb[2];
    if (threadIdx.x == 0) {
        int lo = 0, hi = NN;
        while (lo < hi) { int m = (lo + hi) >> 1; if (batch[m] < g) lo = m + 1; else hi = m; }
        sb[0] = lo;
        lo = 0; hi = NN;
        while (lo < hi) { int m = (lo + hi) >> 1; if (batch[m] < g + 1) lo = m + 1; else hi = m; }
        sb[1] = lo;
    }
    __syncthreads();
    int start = sb[0], end = sb[1];
    int c = threadIdx.x & 31, grp = threadIdx.x >> 5;
    float acc = 0.0f;
    for (int n = start + grp; n < end; n += 32)
        acc += bf2f(h3[(size_t)n * 32 + c]);
    __shared__ float red[32 * 32];
    red[grp * 32 + c] = acc;
    __syncthreads();
    __shared__ float pooled[32];
    if (threadIdx.x < 32) {
        float s = 0.0f;
#pragma unroll
        for (int gr = 0; gr < 32; ++gr) s += red[gr * 32 + threadIdx.x];
        pooled[threadIdx.x] = s / fmaxf((float)(end - start), 1.0f);
    }
    __syncthreads();
    __shared__ float slog[8];
    if (threadIdx.x < 8) {
        float l = bout[threadIdx.x];
#pragma unroll
        for (int k = 0; k < 32; ++k) l = fmaf(pooled[k], Wout[k * 8 + threadIdx.x], l);
        slog[threadIdx.x] = l;
    }
    __syncthreads();
    if (threadIdx.x < 8) {
        float m = slog[0];
#pragma unroll
        for (int i = 1; i < 8; ++i) m = fmaxf(m, slog[i]);
        float s = 0.0f;
#pragma unroll
        for (int i = 0; i < 8; ++i) s += expf(slog[i] - m);
        out[g * NC + threadIdx.x] = slog[threadIdx.x] - m - logf(s);
    }
}

__global__ __launch_bounds__(256) void k_pscan(const int* __restrict__ pcnt,
                                               int* __restrict__ pbase) {
    __shared__ int s[P];
    int tid = threadIdx.x;
    int v = pcnt[tid];
    s[tid] = v;
    __syncthreads();
#pragma unroll
    for (int d = 1; d < P; d <<= 1) {
        int t = (tid >= d) ? s[tid - d] : 0;
        __syncthreads();
        s[tid] += t;
        __syncthreads();
    }
    pbase[tid] = s[tid] - v;
}

extern "C" void kernel_launch(void* const* d_in, const int* in_sizes, int n_in,
                              void* d_out, int out_size, void* d_ws, size_t ws_size,
                              hipStream_t stream) {
    const float* x     = (const float*)d_in[0];
    const int*   eidx  = (const int*)d_in[1];
    const float* ew    = (const float*)d_in[2];
    const int*   batch = (const int*)d_in[3];
    const float* W1 = (const float*)d_in[4];
    const float* b1 = (const float*)d_in[5];
    const float* W2 = (const float*)d_in[6];
    const float* b2 = (const float*)d_in[7];
    const float* W3 = (const float*)d_in[8];
    const float* b3 = (const float*)d_in[9];
    const float* Wout = (const float*)d_in[10];
    const float* bout = (const float*)d_in[11];
    float* out = (float*)d_out;

    const int* row = eidx;        // sources
    const int* col = eidx + NE;   // targets

    // layout: B1 bf16 | B2 bf16 | pairs(CSR) | staging | dinv | off | cntg | pcnt | pbase
    unsigned short* B1 = (unsigned short*)d_ws;                  // 6.4 MB
    unsigned short* B2 = B1 + (size_t)NN * HD;                   // 6.4 MB
    float2* pairs = (float2*)(B2 + (size_t)NN * HD);             // 12.8 MB
    uint2* staging = (uint2*)(pairs + NE);                       // 14.3 MB
    float* dinv = (float*)(staging + (size_t)P * SCAP);          // 0.4 MB
    int* off  = (int*)(dinv + NN);                               // 0.4 MB
    int* cntg = off + NN;                                        // 0.4 MB
    int* pcnt = cntg + NN;                                       // 1 KB
    int* pbase = pcnt + P;

    hipMemsetAsync(pcnt, 0, P * sizeof(int), stream);
    k_bin<<<NBIN, 256, 0, stream>>>(row, col, ew, pcnt, staging);
    k_pscan<<<1, P, 0, stream>>>(pcnt, pbase);
    k_csrA_gemm0<<<P + GEMM0_BLOCKS, 256, 0, stream>>>(pcnt, pbase, staging,
                                                       off, cntg, dinv, x, W1, B1);
    k_csr_b<<<P, 512, 0, stream>>>(pcnt, staging, off, dinv, pairs);
    k_gather<0><<<NORM_BLOCKS, 256, 0, stream>>>(B1, off, cntg, dinv, pairs, b1, W2, B2);
    k_gather<0><<<NORM_BLOCKS, 256, 0, stream>>>(B2, off, cntg, dinv, pairs, b2, W3, B1);
    k_gather<1><<<NORM_BLOCKS, 256, 0, stream>>>(B1, off, cntg, dinv, pairs, b3, nullptr, B2);
    k_pool_head<<<NG, 1024, 0, stream>>>(B2, batch, Wout, bout, out);
}